// Round 10
// baseline (3502.402 us; speedup 1.0000x reference)
//
#include <hip/hip_runtime.h>
#include <hip/hip_bf16.h>
#include <math.h>

typedef __hip_bfloat16 bf16;

#define B_ 16
#define L_ 2048
#define DM 256
#define DI 512
#define NH 8
#define HD 64
#define DS 64
#define CD 640
#define DIP 1160
#define XB 648
#define NL 4
#define Q_ 64
#define NCH 32
#define MROWS (B_*L_)
#define EPS_ 1e-5f
#define NIN 17
#define NSMALL 14
#define STGOFF 32
#define HMPOFF 28552
#define SLICEOFF 94088

__device__ __forceinline__ float u2f(unsigned short u){ return __uint_as_float(((unsigned)u)<<16); }
__device__ __forceinline__ float sigmoidf_(float x){ return 1.f/(1.f+expf(-x)); }
__device__ __forceinline__ float siluf_(float x){ return x*sigmoidf_(x); }
__device__ __forceinline__ float softplusf_(float x){ return (x>20.f)? x : log1pf(expf(x)); }

__device__ const int kN17[NIN] = {1507328,11776,256,1187840,10240,2560,32,32,32,2048,524288,256,256,256,1,768,3};
__device__ const int sIdx[NSMALL] = {1,2,4,5,6,7,8,9,11,12,13,14,15,16};
__device__ const int sNum[NSMALL] = {11776,256,10240,2560,32,32,32,2048,256,256,256,1,768,3};
__device__ const int sOff[NSMALL] = {0,11776,12032,22272,24832,24864,24896,24928,26976,27232,27488,27744,27748,28516};

struct PtrTab { const void* p[NIN]; };

// ---- sentinel writer (diagnostic channel, fp32 out) ----
__global__ __launch_bounds__(64) void k_sentinel(float* out, float v){
    int t = threadIdx.x;
    out[t] = (t==0) ? v : 0.f;
}

// ---- dtype detector: per input, decide fp32 vs bf16 from its bf16-view ----
__global__ __launch_bounds__(256) void k_detect(PtrTab t, int* flags){
    int i = blockIdx.x;
    int n = kN17[i];
    int S = n < 4096 ? n : 4096;
    const unsigned short* u = (const unsigned short*)t.p[i];
    __shared__ int big, ze, zo, so;
    if (threadIdx.x == 0){ big=0; ze=0; zo=0; so=0; }
    __syncthreads();
    int lbig=0, lze=0, lzo=0, lso=0;
    for (int j=threadIdx.x; j<S; j+=256){
        unsigned short v = u[j];
        int e = (v>>7)&0xFF;
        if (e >= 131) lbig = 1;     // |x|>=16 or inf/nan: impossible for legit bf16 data here
        int isz = ((v & 0x7FFF) == 0) ? 1 : 0;
        if (j & 1){ lso++; lzo += isz; } else { lze += isz; }
    }
    if (lbig) atomicOr(&big, 1);
    atomicAdd(&ze, lze); atomicAdd(&zo, lzo); atomicAdd(&so, lso);
    __syncthreads();
    if (threadIdx.x == 0){
        int Se = S - so;
        // fp32 if junk exponents, or fp32-"ones"-like pattern (even halves ~zero, odd not)
        flags[i] = (big || (so > 0 && 4*ze >= 3*Se && 4*zo <= so)) ? 1 : 0;
    }
}

// ---- stage the 14 small arrays to fp32 ----
__global__ __launch_bounds__(256) void k_stage(PtrTab t, const int* __restrict__ flags,
                                               float* __restrict__ stg){
    int a = blockIdx.y;
    int idx = sIdx[a];
    int n = sNum[a];
    float* dst = stg + sOff[a];
    const void* p = t.p[idx];
    if (flags[idx]){
        const float* s = (const float*)p;
        for (int j=blockIdx.x*256+threadIdx.x; j<n; j += gridDim.x*256) dst[j] = s[j];
    } else {
        const unsigned short* s = (const unsigned short*)p;
        for (int j=blockIdx.x*256+threadIdx.x; j<n; j += gridDim.x*256) dst[j] = u2f(s[j]);
    }
}

__device__ __forceinline__ float blockSum256(float v, float* red){
    #pragma unroll
    for (int off=32; off>0; off>>=1) v += __shfl_down(v, off);
    if ((threadIdx.x & 63) == 0) red[threadIdx.x >> 6] = v;
    __syncthreads();
    float s = red[0] + red[1] + red[2] + red[3];
    __syncthreads();
    return s;
}

// ---------------- K1: h = x @ inp_w + inp_b (x raw, dtype-dispatched) ----------------
__global__ __launch_bounds__(256) void k_inproj(const void* __restrict__ x,
                                                const int* __restrict__ flags,
                                                size_t xoff,
                                                const float* __restrict__ w,
                                                const float* __restrict__ bias,
                                                float* __restrict__ h){
    __shared__ float xs[46];
    int row = blockIdx.x;
    int t = threadIdx.x;
    bool f32 = flags[0] != 0;
    if (t < 46){
        size_t j = xoff + (size_t)row*46 + t;
        xs[t] = f32 ? ((const float*)x)[j] : u2f(((const unsigned short*)x)[j]);
    }
    __syncthreads();
    float acc = bias[t];
    #pragma unroll 2
    for (int k=0;k<46;k++) acc += xs[k]*w[k*DM + t];
    h[(size_t)row*DM + t] = acc;
}

// ------- tiled GEMM: C[M,N] = A[M,K f32] @ B[K,N raw dtype-dispatched] (+C) -------
template<bool RES>
__global__ __launch_bounds__(256) void k_gemm(const float* __restrict__ A,
                                              const void* __restrict__ Bw,
                                              const int* __restrict__ flagB,
                                              size_t boff,
                                              float* __restrict__ C,
                                              int N, int K, int ldb, int ldc){
    __shared__ float As[8][128];
    __shared__ float Bs[8][128];
    bool f32 = flagB[0] != 0;
    int tid = threadIdx.x;
    int nbase = blockIdx.x*128, mbase = blockIdx.y*128;
    int mi = tid >> 4, ni = tid & 15;
    int m0 = mi*8, n0 = ni*8;
    float acc[8][8] = {};
    int arow = tid >> 1, akc = (tid & 1)*4;
    int brow = tid >> 5, bnc = (tid & 31)*4;
    for (int kt=0; kt<K; kt+=8){
        float4 av = *(const float4*)&A[(size_t)(mbase+arow)*K + kt + akc];
        float4 bv = make_float4(0.f,0.f,0.f,0.f);
        if (nbase + bnc < N){
            size_t j = boff + (size_t)(kt+brow)*ldb + nbase + bnc;
            if (f32) bv = *(const float4*)&((const float*)Bw)[j];
            else {
                ushort4 bu = *(const ushort4*)&((const unsigned short*)Bw)[j];
                bv = make_float4(u2f(bu.x),u2f(bu.y),u2f(bu.z),u2f(bu.w));
            }
        }
        __syncthreads();
        As[akc+0][arow]=av.x; As[akc+1][arow]=av.y; As[akc+2][arow]=av.z; As[akc+3][arow]=av.w;
        *(float4*)&Bs[brow][bnc] = bv;
        __syncthreads();
        #pragma unroll
        for (int k=0;k<8;k++){
            float4 a0 = *(const float4*)&As[k][m0];
            float4 a1 = *(const float4*)&As[k][m0+4];
            float4 b0 = *(const float4*)&Bs[k][n0];
            float4 b1 = *(const float4*)&Bs[k][n0+4];
            float am[8] = {a0.x,a0.y,a0.z,a0.w,a1.x,a1.y,a1.z,a1.w};
            float bn[8] = {b0.x,b0.y,b0.z,b0.w,b1.x,b1.y,b1.z,b1.w};
            #pragma unroll
            for (int i=0;i<8;i++)
                #pragma unroll
                for (int j=0;j<8;j++) acc[i][j] += am[i]*bn[j];
        }
    }
    #pragma unroll
    for (int i=0;i<8;i++){
        size_t r = (size_t)(mbase+m0+i)*ldc;
        #pragma unroll
        for (int j=0;j<8;j+=4){
            int ng = nbase+n0+j;
            if (ng < N){
                float4 v = make_float4(acc[i][j],acc[i][j+1],acc[i][j+2],acc[i][j+3]);
                if (RES){
                    float4 o = *(const float4*)&C[r+ng];
                    v.x+=o.x; v.y+=o.y; v.z+=o.z; v.w+=o.w;
                }
                *(float4*)&C[r+ng] = v;
            }
        }
    }
}

// ---------------- K3: depthwise causal conv(4) + bias + SiLU ----------------
__global__ __launch_bounds__(256) void k_conv(const float* __restrict__ xb,
                                              const float* __restrict__ cw,
                                              const float* __restrict__ cb,
                                              float* __restrict__ xc){
    int idx = blockIdx.x*256 + threadIdx.x;
    int c = idx % CD;
    int bl = idx / CD;
    int l = bl & (L_-1);
    float acc = cb[c];
    #pragma unroll
    for (int j=0;j<4;j++){
        int l2 = l - 3 + j;
        if (l2 >= 0) acc += xb[(size_t)(bl-3+j)*XB + c] * cw[c*4 + j];
    }
    xc[(size_t)bl*CD + c] = siluf_(acc);
}

// ------- K3b: dt = softplus(raw + dtb), cum = per-chunk cumsum(dt*A) -------
__global__ __launch_bounds__(64) void k_dtcum(const float* __restrict__ xb,
                                              const float* __restrict__ dtb,
                                              const float* __restrict__ alog,
                                              float* __restrict__ dto,
                                              float* __restrict__ cumo){
    int kk = blockIdx.x, h = blockIdx.y, b = blockIdx.z;
    int t = threadIdx.x;
    int l = kk*Q_ + t;
    float raw = xb[(size_t)(b*L_ + l)*XB + CD + h];
    float dtv = softplusf_(raw + dtb[h]);
    float A = -expf(alog[h]);
    float s = dtv * A;
    #pragma unroll
    for (int off=1; off<64; off<<=1){
        float u = __shfl_up(s, off);
        if (t >= off) s += u;
    }
    int base = (b*NH + h)*L_ + l;
    dto[base] = dtv;
    cumo[base] = s;
}

// ------- K4: pass A — intra-chunk scores, y_local (+D*x), S_local -------
__global__ __launch_bounds__(256) void k_passA(const float* __restrict__ xc,
                                               const float* __restrict__ dt,
                                               const float* __restrict__ cum,
                                               const float* __restrict__ Dp,
                                               float* __restrict__ y,
                                               float* __restrict__ S){
    __shared__ float ldsBt[64*68];   // Bt[n][s]
    __shared__ float ldsCX[64*68];   // Ct[n][t] then X[s][p]
    __shared__ float ldsM[64*68];    // MT[s][t]
    __shared__ float sdt[64], scum[64], sw[64];
    int kk = blockIdx.x, h = blockIdx.y, b = blockIdx.z;
    int tid = threadIdx.x;
    int bh = b*NH + h;
    int l0 = kk*Q_;
    int sb = (tid >> 4) << 2;
    int nb = (tid & 15) << 2;
    float4 xr[4];
    #pragma unroll
    for (int i=0;i<4;i++){
        size_t rowbase = (size_t)(b*L_ + l0 + sb + i)*CD;
        float4 bv = *(const float4*)&xc[rowbase + DI + nb];
        float4 cv = *(const float4*)&xc[rowbase + DI + DS + nb];
        xr[i] = *(const float4*)&xc[rowbase + h*HD + nb];
        ldsBt[(nb+0)*68 + sb+i] = bv.x; ldsBt[(nb+1)*68 + sb+i] = bv.y;
        ldsBt[(nb+2)*68 + sb+i] = bv.z; ldsBt[(nb+3)*68 + sb+i] = bv.w;
        ldsCX[(nb+0)*68 + sb+i] = cv.x; ldsCX[(nb+1)*68 + sb+i] = cv.y;
        ldsCX[(nb+2)*68 + sb+i] = cv.z; ldsCX[(nb+3)*68 + sb+i] = cv.w;
    }
    if (tid < 64){
        int base = bh*L_ + l0;
        sdt[tid] = dt[base + tid];
        scum[tid] = cum[base + tid];
    }
    __syncthreads();
    if (tid < 64) sw[tid] = sdt[tid]*expf(fminf(scum[63]-scum[tid], 0.f));
    int t0 = sb, s0 = nb;
    float macc[4][4] = {};
    #pragma unroll 4
    for (int n=0;n<64;n++){
        float4 cv = *(const float4*)&ldsCX[n*68 + t0];
        float4 bv = *(const float4*)&ldsBt[n*68 + s0];
        float cs[4] = {cv.x,cv.y,cv.z,cv.w};
        float bs[4] = {bv.x,bv.y,bv.z,bv.w};
        #pragma unroll
        for (int i=0;i<4;i++)
            #pragma unroll
            for (int j=0;j<4;j++) macc[i][j] += cs[i]*bs[j];
    }
    #pragma unroll
    for (int i=0;i<4;i++){
        float ct = scum[t0+i];
        #pragma unroll
        for (int j=0;j<4;j++){
            int s = s0+j, t = t0+i;
            float m = (s <= t) ? macc[i][j]*sdt[s]*expf(fminf(ct - scum[s], 0.f)) : 0.f;
            ldsM[s*68 + t] = m;
        }
    }
    __syncthreads();
    #pragma unroll
    for (int i=0;i<4;i++) *(float4*)&ldsCX[(sb+i)*68 + nb] = xr[i];  // X[s][p]
    __syncthreads();
    float yacc[4][4] = {};
    #pragma unroll 4
    for (int s=0;s<64;s++){
        float4 mv = *(const float4*)&ldsM[s*68 + t0];
        float4 xv = *(const float4*)&ldsCX[s*68 + nb];
        float ms[4] = {mv.x,mv.y,mv.z,mv.w};
        float xs4[4] = {xv.x,xv.y,xv.z,xv.w};
        #pragma unroll
        for (int i=0;i<4;i++)
            #pragma unroll
            for (int j=0;j<4;j++) yacc[i][j] += ms[i]*xs4[j];
    }
    float Dh = Dp[h];
    #pragma unroll
    for (int i=0;i<4;i++){
        float4 xv = *(const float4*)&ldsCX[(t0+i)*68 + nb];
        float4 o;
        o.x = yacc[i][0] + Dh*xv.x;
        o.y = yacc[i][1] + Dh*xv.y;
        o.z = yacc[i][2] + Dh*xv.z;
        o.w = yacc[i][3] + Dh*xv.w;
        *(float4*)&y[(size_t)(b*L_ + l0 + t0 + i)*DI + h*HD + nb] = o;
    }
    float sacc[4][4] = {};
    #pragma unroll 2
    for (int s=0;s<64;s++){
        float w = sw[s];
        float4 xv = *(const float4*)&ldsCX[s*68 + nb];
        float bsv[4];
        #pragma unroll
        for (int i=0;i<4;i++) bsv[i] = w*ldsBt[(sb+i)*68 + s];
        float xs4[4] = {xv.x,xv.y,xv.z,xv.w};
        #pragma unroll
        for (int i=0;i<4;i++)
            #pragma unroll
            for (int j=0;j<4;j++) sacc[i][j] += bsv[i]*xs4[j];
    }
    size_t Sbase = ((size_t)bh*NCH + kk)*4096;
    #pragma unroll
    for (int i=0;i<4;i++){
        float4 v = make_float4(sacc[i][0],sacc[i][1],sacc[i][2],sacc[i][3]);
        *(float4*)&S[Sbase + (sb+i)*64 + nb] = v;
    }
}

// ------- K5: sequential chunk-state combine (in-place S_local -> S_in) -------
__global__ __launch_bounds__(256) void k_combine(const float* __restrict__ cum,
                                                 float* __restrict__ S){
    int h = blockIdx.x, b = blockIdx.y;
    int bh = b*NH + h;
    int tid = threadIdx.x;
    float4 st[4];
    #pragma unroll
    for (int i=0;i<4;i++) st[i] = make_float4(0.f,0.f,0.f,0.f);
    size_t base0 = ((size_t)bh*NCH)*4096 + (size_t)tid*16;
    for (int k=0;k<NCH;k++){
        size_t base = base0 + (size_t)k*4096;
        float dk = expf(fminf(cum[bh*L_ + k*Q_ + 63], 0.f));
        float4 a[4];
        #pragma unroll
        for (int i=0;i<4;i++) a[i] = *(const float4*)&S[base + i*4];
        #pragma unroll
        for (int i=0;i<4;i++) *(float4*)&S[base + i*4] = st[i];
        #pragma unroll
        for (int i=0;i<4;i++){
            st[i].x = a[i].x + dk*st[i].x;
            st[i].y = a[i].y + dk*st[i].y;
            st[i].z = a[i].z + dk*st[i].z;
            st[i].w = a[i].w + dk*st[i].w;
        }
    }
}

// ------- K6: finalize — y += exp(cum_t) * C_t @ S_in -------
__global__ __launch_bounds__(256) void k_finalize(const float* __restrict__ xc,
                                                  const float* __restrict__ cum,
                                                  const float* __restrict__ S,
                                                  float* __restrict__ y){
    __shared__ float ldsCt[64*68];
    __shared__ float ldsS[64*68];
    __shared__ float scum[64];
    int kk = blockIdx.x, h = blockIdx.y, b = blockIdx.z;
    int tid = threadIdx.x;
    int bh = b*NH + h;
    int l0 = kk*Q_;
    int sb = (tid >> 4) << 2, nb = (tid & 15) << 2;
    #pragma unroll
    for (int i=0;i<4;i++){
        size_t rowbase = (size_t)(b*L_ + l0 + sb + i)*CD;
        float4 cv = *(const float4*)&xc[rowbase + DI + DS + nb];
        ldsCt[(nb+0)*68 + sb+i] = cv.x; ldsCt[(nb+1)*68 + sb+i] = cv.y;
        ldsCt[(nb+2)*68 + sb+i] = cv.z; ldsCt[(nb+3)*68 + sb+i] = cv.w;
    }
    size_t Sbase = ((size_t)bh*NCH + kk)*4096;
    {
        int n = tid >> 2, p0 = (tid & 3)*16;
        #pragma unroll
        for (int i=0;i<4;i++)
            *(float4*)&ldsS[n*68 + p0 + i*4] = *(const float4*)&S[Sbase + n*64 + p0 + i*4];
    }
    if (tid < 64) scum[tid] = cum[bh*L_ + l0 + tid];
    __syncthreads();
    int t0 = sb, p0 = nb;
    float acc[4][4] = {};
    #pragma unroll 4
    for (int n=0;n<64;n++){
        float4 cv = *(const float4*)&ldsCt[n*68 + t0];
        float4 sv = *(const float4*)&ldsS[n*68 + p0];
        float cs[4] = {cv.x,cv.y,cv.z,cv.w};
        float ss[4] = {sv.x,sv.y,sv.z,sv.w};
        #pragma unroll
        for (int i=0;i<4;i++)
            #pragma unroll
            for (int j=0;j<4;j++) acc[i][j] += cs[i]*ss[j];
    }
    #pragma unroll
    for (int i=0;i<4;i++){
        float e = expf(fminf(scum[t0+i], 0.f));
        size_t yi = (size_t)(b*L_ + l0 + t0 + i)*DI + h*HD + p0;
        float4 o = *(const float4*)&y[yi];
        o.x += e*acc[i][0]; o.y += e*acc[i][1]; o.z += e*acc[i][2]; o.w += e*acc[i][3];
        *(float4*)&y[yi] = o;
    }
}

// ------- K7: gate (y *= silu(z)) + RMSNorm * rms_w -------
__global__ __launch_bounds__(256) void k_gaterms(const float* __restrict__ z,
                                                 const float* __restrict__ rw,
                                                 float* __restrict__ y){
    __shared__ float red[4];
    int row = blockIdx.x;
    int tid = threadIdx.x;
    float g[2]; float ss = 0.f;
    #pragma unroll
    for (int r=0;r<2;r++){
        int d = tid + r*256;
        float zv = z[(size_t)row*DI + d];
        float yv = y[(size_t)row*DI + d];
        float gv = yv * siluf_(zv);
        g[r] = gv;
        ss += gv*gv;
    }
    float tot = blockSum256(ss, red);
    float rinv = rsqrtf(tot*(1.f/512.f) + EPS_);
    #pragma unroll
    for (int r=0;r<2;r++){
        int d = tid + r*256;
        y[(size_t)row*DI + d] = g[r]*rinv*rw[d];
    }
}

// ------- K9a: LayerNorm rows -------
__global__ __launch_bounds__(256) void k_ln(const float* __restrict__ h,
                                            const float* __restrict__ lw,
                                            const float* __restrict__ lb,
                                            float* __restrict__ out){
    __shared__ float red[4];
    int row = blockIdx.x;
    int tid = threadIdx.x;
    float v = h[(size_t)row*DM + tid];
    float mu = blockSum256(v, red)*(1.f/256.f);
    float d = v - mu;
    float var = blockSum256(d*d, red)*(1.f/256.f);
    out[(size_t)row*DM + tid] = d*rsqrtf(var + EPS_)*lw[tid] + lb[tid];
}

// ------- K9b: partial mean over L -------
__global__ __launch_bounds__(256) void k_meanl(const float* __restrict__ ln,
                                               float* __restrict__ hmp,
                                               int b0){
    int g = blockIdx.x, bl = blockIdx.y;
    int tid = threadIdx.x;
    float s = 0.f;
    for (int i=0;i<128;i++){
        int l = g*128 + i;
        s += ln[(size_t)(bl*L_ + l)*DM + tid];
    }
    hmp[((size_t)(b0+bl)*16 + g)*DM + tid] = s*(1.f/2048.f);
}

// ------- K10: output heads (FP32 out — the round-10 fix) -------
__global__ __launch_bounds__(256) void k_heads(const float* __restrict__ hmp,
                                               const float* __restrict__ dw,
                                               const float* __restrict__ db,
                                               const float* __restrict__ rw,
                                               const float* __restrict__ rb,
                                               float* __restrict__ out){
    __shared__ float red[4];
    int b = blockIdx.x;
    int tid = threadIdx.x;
    float hv = 0.f;
    #pragma unroll
    for (int g=0; g<16; g++) hv += hmp[((size_t)b*16 + g)*DM + tid];
    float s0 = hv*dw[tid];
    float s1 = hv*rw[tid*3+0];
    float s2 = hv*rw[tid*3+1];
    float s3 = hv*rw[tid*3+2];
    s0 = blockSum256(s0, red);
    s1 = blockSum256(s1, red);
    s2 = blockSum256(s2, red);
    s3 = blockSum256(s3, red);
    if (tid == 0){
        out[b] = s0 + db[0];
        out[16 + b*3 + 0] = s1 + rb[0];
        out[16 + b*3 + 1] = s2 + rb[1];
        out[16 + b*3 + 2] = s3 + rb[2];
    }
}

extern "C" void kernel_launch(void* const* d_in, const int* in_sizes, int n_in,
                              void* d_out, int out_size, void* d_ws, size_t ws_size,
                              hipStream_t stream){
    static const int expSizes[NIN] = {1507328,11776,256,1187840,10240,2560,32,32,32,2048,524288,256,256,256,1,768,3};
    float* out = (float*)d_out;

    if (n_in != NIN){
        k_sentinel<<<1,64,0,stream>>>(out, 9.0e6f);
        return;
    }
    for (int i=0;i<NIN;i++){
        if (in_sizes[i] != expSizes[i]){
            k_sentinel<<<1,64,0,stream>>>(out, (float)(i+1)*1.0e5f);
            return;
        }
    }
    size_t need16 = ((size_t)SLICEOFF + 2048ull*2584ull)*4ull;
    if (ws_size < need16){
        float mb = (float)(ws_size >> 20);
        k_sentinel<<<1,64,0,stream>>>(out, 2.0e7f + mb*131072.f);
        return;
    }

    float* ws = (float*)d_ws;
    int* flags = (int*)d_ws;
    float* stg = ws + STGOFF;
    float* hmp = ws + HMPOFF;

    PtrTab pt;
    for (int i=0;i<NIN;i++) pt.p[i] = d_in[i];

    k_detect<<<NIN, 256, 0, stream>>>(pt, flags);
    k_stage<<<dim3(8, NSMALL), 256, 0, stream>>>(pt, flags, stg);

    const float* inp_w = stg + 0;
    const float* inp_b = stg + 11776;
    const float* cw    = stg + 12032;
    const float* cb    = stg + 22272;
    const float* dtb   = stg + 24832;
    const float* alog  = stg + 24864;
    const float* Dp    = stg + 24896;
    const float* rmsw  = stg + 24928;
    const float* lnw   = stg + 26976;
    const float* lnb   = stg + 27232;
    const float* dw    = stg + 27488;
    const float* db    = stg + 27744;
    const float* rw    = stg + 27748;
    const float* rb    = stg + 28516;

    int nsl = 1;
    while (((size_t)SLICEOFF + ((size_t)MROWS/nsl)*2584ull)*4ull > ws_size) nsl <<= 1;
    const size_t R = (size_t)MROWS / nsl;
    const int SB = B_ / nsl;

    float* base = ws + SLICEOFF;
    float* hbuf = base;                     // R*256
    float* z    = hbuf + R*DM;              // R*512
    float* xb   = z + R*DI;                 // R*648, later aliased as y (R*512 view)
    float* yb   = xb;
    float* xcb  = xb + R*XB;                // R*640
    float* S    = xcb + R*CD;               // R*512
    float* dt   = S + R*DI;                 // R*8
    float* cum  = dt + R*NH;                // R*8

    for (int sl=0; sl<nsl; sl++){
        k_inproj<<<(int)R, 256, 0, stream>>>(d_in[0], flags, (size_t)sl*R*46, inp_w, inp_b, hbuf);
        for (int li=0; li<NL; li++){
            size_t wof = (size_t)li*DM*DIP;
            k_gemm<false><<<dim3(4, R/128), 256, 0, stream>>>(hbuf, d_in[3], flags+3, wof, z, DI, DM, DIP, DI);
            k_gemm<false><<<dim3(6, R/128), 256, 0, stream>>>(hbuf, d_in[3], flags+3, wof+DI, xb, XB, DM, DIP, XB);
            k_conv<<<(int)((R*CD)/256), 256, 0, stream>>>(xb, cw + li*CD*4, cb + li*CD, xcb);
            k_dtcum<<<dim3(NCH,NH,SB), 64, 0, stream>>>(xb, dtb + li*NH, alog + li*NH, dt, cum);
            k_passA<<<dim3(NCH,NH,SB), 256, 0, stream>>>(xcb, dt, cum, Dp + li*NH, yb, S);
            k_combine<<<dim3(NH,SB), 256, 0, stream>>>(cum, S);
            k_finalize<<<dim3(NCH,NH,SB), 256, 0, stream>>>(xcb, cum, S, yb);
            k_gaterms<<<(int)R, 256, 0, stream>>>(z, rmsw + li*DI, yb);
            k_gemm<true><<<dim3(2, R/128), 256, 0, stream>>>(yb, d_in[10], flags+10, (size_t)li*DI*DM, hbuf, DM, DI, DM, DM);
        }
        k_ln<<<(int)R, 256, 0, stream>>>(hbuf, lnw, lnb, z);
        k_meanl<<<dim3(16,SB), 256, 0, stream>>>(z, hmp, sl*SB);
    }
    k_heads<<<B_, 256, 0, stream>>>(hmp, dw, db, rw, rb, out);
}

// Round 12
// 2247.650 us; speedup vs baseline: 1.5583x; 1.5583x over previous
//
#include <hip/hip_runtime.h>
#include <hip/hip_bf16.h>
#include <math.h>

typedef __hip_bfloat16 bf16;

#define B_ 16
#define L_ 2048
#define DM 256
#define DI 512
#define NH 8
#define HD 64
#define DS 64
#define CD 640
#define DIP 1160
#define XB 648
#define NP 1280
#define NL 4
#define Q_ 64
#define NCH 32
#define MROWS (B_*L_)
#define EPS_ 1e-5f
#define NIN 17
#define NSMALL 14
#define STGOFF 32
#define WIPT 28552
#define WOPT 683912
#define HMPOFF 946056
#define SLICEOFF 1011592
#define PERROW 2968

__device__ __forceinline__ float u2f(unsigned short u){ return __uint_as_float(((unsigned)u)<<16); }
__device__ __forceinline__ unsigned short f2bu(float f){ bf16 h = __float2bfloat16(f); return *(unsigned short*)&h; }
__device__ __forceinline__ float sigmoidf_(float x){ return 1.f/(1.f+expf(-x)); }
__device__ __forceinline__ float siluf_(float x){ return x*sigmoidf_(x); }
__device__ __forceinline__ float softplusf_(float x){ return (x>20.f)? x : log1pf(expf(x)); }

typedef __attribute__((ext_vector_type(8))) short short8v;
typedef __attribute__((ext_vector_type(4))) float float4v;

__device__ const int kN17[NIN] = {1507328,11776,256,1187840,10240,2560,32,32,32,2048,524288,256,256,256,1,768,3};
__device__ const int sIdx[NSMALL] = {1,2,4,5,6,7,8,9,11,12,13,14,15,16};
__device__ const int sNum[NSMALL] = {11776,256,10240,2560,32,32,32,2048,256,256,256,1,768,3};
__device__ const int sOff[NSMALL] = {0,11776,12032,22272,24832,24864,24896,24928,26976,27232,27488,27744,27748,28516};

struct PtrTab { const void* p[NIN]; };

// ---- sentinel writer (diagnostic channel, fp32 out) ----
__global__ __launch_bounds__(64) void k_sentinel(float* out, float v){
    int t = threadIdx.x;
    out[t] = (t==0) ? v : 0.f;
}

// ---- dtype detector: per input, decide fp32 vs bf16 from its bf16-view ----
__global__ __launch_bounds__(256) void k_detect(PtrTab t, int* flags){
    int i = blockIdx.x;
    int n = kN17[i];
    int S = n < 4096 ? n : 4096;
    const unsigned short* u = (const unsigned short*)t.p[i];
    __shared__ int big, ze, zo, so;
    if (threadIdx.x == 0){ big=0; ze=0; zo=0; so=0; }
    __syncthreads();
    int lbig=0, lze=0, lzo=0, lso=0;
    for (int j=threadIdx.x; j<S; j+=256){
        unsigned short v = u[j];
        int e = (v>>7)&0xFF;
        if (e >= 131) lbig = 1;
        int isz = ((v & 0x7FFF) == 0) ? 1 : 0;
        if (j & 1){ lso++; lzo += isz; } else { lze += isz; }
    }
    if (lbig) atomicOr(&big, 1);
    atomicAdd(&ze, lze); atomicAdd(&zo, lzo); atomicAdd(&so, lso);
    __syncthreads();
    if (threadIdx.x == 0){
        int Se = S - so;
        flags[i] = (big || (so > 0 && 4*ze >= 3*Se && 4*zo <= so)) ? 1 : 0;
    }
}

// ---- stage the 14 small arrays to fp32 ----
__global__ __launch_bounds__(256) void k_stage(PtrTab t, const int* __restrict__ flags,
                                               float* __restrict__ stg){
    int a = blockIdx.y;
    int idx = sIdx[a];
    int n = sNum[a];
    float* dst = stg + sOff[a];
    const void* p = t.p[idx];
    if (flags[idx]){
        const float* s = (const float*)p;
        for (int j=blockIdx.x*256+threadIdx.x; j<n; j += gridDim.x*256) dst[j] = s[j];
    } else {
        const unsigned short* s = (const unsigned short*)p;
        for (int j=blockIdx.x*256+threadIdx.x; j<n; j += gridDim.x*256) dst[j] = u2f(s[j]);
    }
}

// ---- stage in_proj_w transposed+padded: dst[l][n:1280][k:256] bf16 ----
__global__ __launch_bounds__(256) void k_wip(const void* __restrict__ src,
                                             const int* __restrict__ flag,
                                             unsigned short* __restrict__ dst){
    int n = blockIdx.x, l = blockIdx.y, k = threadIdx.x;
    unsigned short b = 0;
    if (n < DIP){
        size_t si = ((size_t)l*DM + k)*DIP + n;
        if (flag[0]) b = f2bu(((const float*)src)[si]);
        else         b = ((const unsigned short*)src)[si];
    }
    dst[((size_t)l*NP + n)*DM + k] = b;
}

// ---- stage out_proj_w transposed: dst[l][n:256][k:512] bf16 ----
__global__ __launch_bounds__(256) void k_wop(const void* __restrict__ src,
                                             const int* __restrict__ flag,
                                             unsigned short* __restrict__ dst){
    int n = blockIdx.x, l = blockIdx.y;
    for (int k = threadIdx.x; k < DI; k += 256){
        size_t si = ((size_t)l*DI + k)*DM + n;
        unsigned short b;
        if (flag[0]) b = f2bu(((const float*)src)[si]);
        else         b = ((const unsigned short*)src)[si];
        dst[((size_t)l*DM + n)*DI + k] = b;
    }
}

__device__ __forceinline__ float blockSum256(float v, float* red){
    #pragma unroll
    for (int off=32; off>0; off>>=1) v += __shfl_down(v, off);
    if ((threadIdx.x & 63) == 0) red[threadIdx.x >> 6] = v;
    __syncthreads();
    float s = red[0] + red[1] + red[2] + red[3];
    __syncthreads();
    return s;
}

// ---------------- K1: h = x @ inp_w + inp_b; writes f32 h and bf16 shadow ----------------
__global__ __launch_bounds__(256) void k_inproj(const void* __restrict__ x,
                                                const int* __restrict__ flags,
                                                size_t xoff,
                                                const float* __restrict__ w,
                                                const float* __restrict__ bias,
                                                float* __restrict__ h,
                                                unsigned short* __restrict__ hbf){
    __shared__ float xs[46];
    int row = blockIdx.x;
    int t = threadIdx.x;
    bool f32 = flags[0] != 0;
    if (t < 46){
        size_t j = xoff + (size_t)row*46 + t;
        xs[t] = f32 ? ((const float*)x)[j] : u2f(((const unsigned short*)x)[j]);
    }
    __syncthreads();
    float acc = bias[t];
    #pragma unroll 2
    for (int k=0;k<46;k++) acc += xs[k]*w[k*DM + t];
    h[(size_t)row*DM + t] = acc;
    hbf[(size_t)row*DM + t] = f2bu(acc);
}

// ------- MFMA GEMM: C[128x128 tiles] = A[M x K bf16] @ Bt[N x K bf16]^T -------
// MODE 0 (in-proj): cols <512 -> z (ld 512); 512..1160 -> xb (ld 648); >=1160 dropped
// MODE 1 (out-proj): O1 (hbuf, ld 256) += acc; O3 (hbf) = bf16(result)
template<int MODE>
__global__ __launch_bounds__(256) void k_mgemm(const unsigned short* __restrict__ A,
                                               const unsigned short* __restrict__ Bt,
                                               float* __restrict__ O1,
                                               float* __restrict__ O2,
                                               unsigned short* __restrict__ O3,
                                               int K){
    __shared__ unsigned short As[128*40];
    __shared__ unsigned short Bs[128*40];
    int tid = threadIdx.x;
    int wave = tid >> 6, lane = tid & 63, quad = lane >> 4, l15 = lane & 15;
    int mbase = blockIdx.y*128, nbase = blockIdx.x*128;
    int wm = (wave & 1)*64, wn = (wave >> 1)*64;
    float4v zero4 = {0.f,0.f,0.f,0.f};
    float4v acc[4][4];
    #pragma unroll
    for (int mi=0;mi<4;mi++)
        #pragma unroll
        for (int ni=0;ni<4;ni++) acc[mi][ni] = zero4;
    for (int k0 = 0; k0 < K; k0 += 32){
        #pragma unroll
        for (int i=0;i<2;i++){
            int c = tid + i*256;
            int row = c >> 2, koff = (c & 3)*8;
            *(uint4*)&As[row*40 + koff] = *(const uint4*)&A[(size_t)(mbase+row)*K + k0 + koff];
            *(uint4*)&Bs[row*40 + koff] = *(const uint4*)&Bt[(size_t)(nbase+row)*K + k0 + koff];
        }
        __syncthreads();
        short8v af[4], bfr[4];
        #pragma unroll
        for (int mi=0;mi<4;mi++) af[mi] = *(const short8v*)&As[(wm + mi*16 + l15)*40 + quad*8];
        #pragma unroll
        for (int ni=0;ni<4;ni++) bfr[ni] = *(const short8v*)&Bs[(wn + ni*16 + l15)*40 + quad*8];
        #pragma unroll
        for (int mi=0;mi<4;mi++)
            #pragma unroll
            for (int ni=0;ni<4;ni++)
                acc[mi][ni] = __builtin_amdgcn_mfma_f32_16x16x32_bf16(af[mi], bfr[ni], acc[mi][ni], 0, 0, 0);
        __syncthreads();
    }
    #pragma unroll
    for (int mi=0;mi<4;mi++){
        #pragma unroll
        for (int ni=0;ni<4;ni++){
            int col = nbase + wn + ni*16 + l15;
            #pragma unroll
            for (int reg=0;reg<4;reg++){
                int grow = mbase + wm + mi*16 + quad*4 + reg;
                float v = acc[mi][ni][reg];
                if (MODE == 0){
                    if (col < DI) O1[(size_t)grow*DI + col] = v;
                    else if (col < DIP) O2[(size_t)grow*XB + (col - DI)] = v;
                } else {
                    float hnew = O1[(size_t)grow*DM + col] + v;
                    O1[(size_t)grow*DM + col] = hnew;
                    O3[(size_t)grow*DM + col] = f2bu(hnew);
                }
            }
        }
    }
}

// ---------------- K3: depthwise causal conv(4) + bias + SiLU ----------------
__global__ __launch_bounds__(256) void k_conv(const float* __restrict__ xb,
                                              const float* __restrict__ cw,
                                              const float* __restrict__ cb,
                                              float* __restrict__ xc){
    int idx = blockIdx.x*256 + threadIdx.x;
    int c = idx % CD;
    int bl = idx / CD;
    int l = bl & (L_-1);
    float acc = cb[c];
    #pragma unroll
    for (int j=0;j<4;j++){
        int l2 = l - 3 + j;
        if (l2 >= 0) acc += xb[(size_t)(bl-3+j)*XB + c] * cw[c*4 + j];
    }
    xc[(size_t)bl*CD + c] = siluf_(acc);
}

// ------- K3b: dt = softplus(raw + dtb), cum = per-chunk cumsum(dt*A) -------
__global__ __launch_bounds__(64) void k_dtcum(const float* __restrict__ xb,
                                              const float* __restrict__ dtb,
                                              const float* __restrict__ alog,
                                              float* __restrict__ dto,
                                              float* __restrict__ cumo){
    int kk = blockIdx.x, h = blockIdx.y, b = blockIdx.z;
    int t = threadIdx.x;
    int l = kk*Q_ + t;
    float raw = xb[(size_t)(b*L_ + l)*XB + CD + h];
    float dtv = softplusf_(raw + dtb[h]);
    float A = -expf(alog[h]);
    float s = dtv * A;
    #pragma unroll
    for (int off=1; off<64; off<<=1){
        float u = __shfl_up(s, off);
        if (t >= off) s += u;
    }
    int base = (b*NH + h)*L_ + l;
    dto[base] = dtv;
    cumo[base] = s;
}

// ------- K4: pass A — intra-chunk scores, y_local (+D*x), S_local -------
__global__ __launch_bounds__(256) void k_passA(const float* __restrict__ xc,
                                               const float* __restrict__ dt,
                                               const float* __restrict__ cum,
                                               const float* __restrict__ Dp,
                                               float* __restrict__ y,
                                               float* __restrict__ S){
    __shared__ float ldsBt[64*68];
    __shared__ float ldsCX[64*68];
    __shared__ float ldsM[64*68];
    __shared__ float sdt[64], scum[64], sw[64];
    int kk = blockIdx.x, h = blockIdx.y, b = blockIdx.z;
    int tid = threadIdx.x;
    int bh = b*NH + h;
    int l0 = kk*Q_;
    int sb = (tid >> 4) << 2;
    int nb = (tid & 15) << 2;
    float4 xr[4];
    #pragma unroll
    for (int i=0;i<4;i++){
        size_t rowbase = (size_t)(b*L_ + l0 + sb + i)*CD;
        float4 bv = *(const float4*)&xc[rowbase + DI + nb];
        float4 cv = *(const float4*)&xc[rowbase + DI + DS + nb];
        xr[i] = *(const float4*)&xc[rowbase + h*HD + nb];
        ldsBt[(nb+0)*68 + sb+i] = bv.x; ldsBt[(nb+1)*68 + sb+i] = bv.y;
        ldsBt[(nb+2)*68 + sb+i] = bv.z; ldsBt[(nb+3)*68 + sb+i] = bv.w;
        ldsCX[(nb+0)*68 + sb+i] = cv.x; ldsCX[(nb+1)*68 + sb+i] = cv.y;
        ldsCX[(nb+2)*68 + sb+i] = cv.z; ldsCX[(nb+3)*68 + sb+i] = cv.w;
    }
    if (tid < 64){
        int base = bh*L_ + l0;
        sdt[tid] = dt[base + tid];
        scum[tid] = cum[base + tid];
    }
    __syncthreads();
    if (tid < 64) sw[tid] = sdt[tid]*expf(fminf(scum[63]-scum[tid], 0.f));
    int t0 = sb, s0 = nb;
    float macc[4][4] = {};
    #pragma unroll 4
    for (int n=0;n<64;n++){
        float4 cv = *(const float4*)&ldsCX[n*68 + t0];
        float4 bv = *(const float4*)&ldsBt[n*68 + s0];
        float cs[4] = {cv.x,cv.y,cv.z,cv.w};
        float bs[4] = {bv.x,bv.y,bv.z,bv.w};
        #pragma unroll
        for (int i=0;i<4;i++)
            #pragma unroll
            for (int j=0;j<4;j++) macc[i][j] += cs[i]*bs[j];
    }
    #pragma unroll
    for (int i=0;i<4;i++){
        float ct = scum[t0+i];
        #pragma unroll
        for (int j=0;j<4;j++){
            int s = s0+j, t = t0+i;
            float m = (s <= t) ? macc[i][j]*sdt[s]*expf(fminf(ct - scum[s], 0.f)) : 0.f;
            ldsM[s*68 + t] = m;
        }
    }
    __syncthreads();
    #pragma unroll
    for (int i=0;i<4;i++) *(float4*)&ldsCX[(sb+i)*68 + nb] = xr[i];
    __syncthreads();
    float yacc[4][4] = {};
    #pragma unroll 4
    for (int s=0;s<64;s++){
        float4 mv = *(const float4*)&ldsM[s*68 + t0];
        float4 xv = *(const float4*)&ldsCX[s*68 + nb];
        float ms[4] = {mv.x,mv.y,mv.z,mv.w};
        float xs4[4] = {xv.x,xv.y,xv.z,xv.w};
        #pragma unroll
        for (int i=0;i<4;i++)
            #pragma unroll
            for (int j=0;j<4;j++) yacc[i][j] += ms[i]*xs4[j];
    }
    float Dh = Dp[h];
    #pragma unroll
    for (int i=0;i<4;i++){
        float4 xv = *(const float4*)&ldsCX[(t0+i)*68 + nb];
        float4 o;
        o.x = yacc[i][0] + Dh*xv.x;
        o.y = yacc[i][1] + Dh*xv.y;
        o.z = yacc[i][2] + Dh*xv.z;
        o.w = yacc[i][3] + Dh*xv.w;
        *(float4*)&y[(size_t)(b*L_ + l0 + t0 + i)*DI + h*HD + nb] = o;
    }
    float sacc[4][4] = {};
    #pragma unroll 2
    for (int s=0;s<64;s++){
        float w = sw[s];
        float4 xv = *(const float4*)&ldsCX[s*68 + nb];
        float bsv[4];
        #pragma unroll
        for (int i=0;i<4;i++) bsv[i] = w*ldsBt[(sb+i)*68 + s];
        float xs4[4] = {xv.x,xv.y,xv.z,xv.w};
        #pragma unroll
        for (int i=0;i<4;i++)
            #pragma unroll
            for (int j=0;j<4;j++) sacc[i][j] += bsv[i]*xs4[j];
    }
    size_t Sbase = ((size_t)bh*NCH + kk)*4096;
    #pragma unroll
    for (int i=0;i<4;i++){
        float4 v = make_float4(sacc[i][0],sacc[i][1],sacc[i][2],sacc[i][3]);
        *(float4*)&S[Sbase + (sb+i)*64 + nb] = v;
    }
}

// ------- K5: sequential chunk-state combine -------
__global__ __launch_bounds__(256) void k_combine(const float* __restrict__ cum,
                                                 float* __restrict__ S){
    int h = blockIdx.x, b = blockIdx.y;
    int bh = b*NH + h;
    int tid = threadIdx.x;
    float4 st[4];
    #pragma unroll
    for (int i=0;i<4;i++) st[i] = make_float4(0.f,0.f,0.f,0.f);
    size_t base0 = ((size_t)bh*NCH)*4096 + (size_t)tid*16;
    for (int k=0;k<NCH;k++){
        size_t base = base0 + (size_t)k*4096;
        float dk = expf(fminf(cum[bh*L_ + k*Q_ + 63], 0.f));
        float4 a[4];
        #pragma unroll
        for (int i=0;i<4;i++) a[i] = *(const float4*)&S[base + i*4];
        #pragma unroll
        for (int i=0;i<4;i++) *(float4*)&S[base + i*4] = st[i];
        #pragma unroll
        for (int i=0;i<4;i++){
            st[i].x = a[i].x + dk*st[i].x;
            st[i].y = a[i].y + dk*st[i].y;
            st[i].z = a[i].z + dk*st[i].z;
            st[i].w = a[i].w + dk*st[i].w;
        }
    }
}

// ------- K6: finalize — y += exp(cum_t) * C_t @ S_in -------
__global__ __launch_bounds__(256) void k_finalize(const float* __restrict__ xc,
                                                  const float* __restrict__ cum,
                                                  const float* __restrict__ S,
                                                  float* __restrict__ y){
    __shared__ float ldsCt[64*68];
    __shared__ float ldsS[64*68];
    __shared__ float scum[64];
    int kk = blockIdx.x, h = blockIdx.y, b = blockIdx.z;
    int tid = threadIdx.x;
    int bh = b*NH + h;
    int l0 = kk*Q_;
    int sb = (tid >> 4) << 2, nb = (tid & 15) << 2;
    #pragma unroll
    for (int i=0;i<4;i++){
        size_t rowbase = (size_t)(b*L_ + l0 + sb + i)*CD;
        float4 cv = *(const float4*)&xc[rowbase + DI + DS + nb];
        ldsCt[(nb+0)*68 + sb+i] = cv.x; ldsCt[(nb+1)*68 + sb+i] = cv.y;
        ldsCt[(nb+2)*68 + sb+i] = cv.z; ldsCt[(nb+3)*68 + sb+i] = cv.w;
    }
    size_t Sbase = ((size_t)bh*NCH + kk)*4096;
    {
        int n = tid >> 2, p0 = (tid & 3)*16;
        #pragma unroll
        for (int i=0;i<4;i++)
            *(float4*)&ldsS[n*68 + p0 + i*4] = *(const float4*)&S[Sbase + n*64 + p0 + i*4];
    }
    if (tid < 64) scum[tid] = cum[bh*L_ + l0 + tid];
    __syncthreads();
    int t0 = sb, p0 = nb;
    float acc[4][4] = {};
    #pragma unroll 4
    for (int n=0;n<64;n++){
        float4 cv = *(const float4*)&ldsCt[n*68 + t0];
        float4 sv = *(const float4*)&ldsS[n*68 + p0];
        float cs[4] = {cv.x,cv.y,cv.z,cv.w};
        float ss[4] = {sv.x,sv.y,sv.z,sv.w};
        #pragma unroll
        for (int i=0;i<4;i++)
            #pragma unroll
            for (int j=0;j<4;j++) acc[i][j] += cs[i]*ss[j];
    }
    #pragma unroll
    for (int i=0;i<4;i++){
        float e = expf(fminf(scum[t0+i], 0.f));
        size_t yi = (size_t)(b*L_ + l0 + t0 + i)*DI + h*HD + p0;
        float4 o = *(const float4*)&y[yi];
        o.x += e*acc[i][0]; o.y += e*acc[i][1]; o.z += e*acc[i][2]; o.w += e*acc[i][3];
        *(float4*)&y[yi] = o;
    }
}

// ------- K7: gate + RMSNorm; emits bf16 y for out-proj MFMA -------
__global__ __launch_bounds__(256) void k_gaterms(const float* __restrict__ z,
                                                 const float* __restrict__ rw,
                                                 const float* __restrict__ y,
                                                 unsigned short* __restrict__ ybf){
    __shared__ float red[4];
    int row = blockIdx.x;
    int tid = threadIdx.x;
    float g[2]; float ss = 0.f;
    #pragma unroll
    for (int r=0;r<2;r++){
        int d = tid + r*256;
        float zv = z[(size_t)row*DI + d];
        float yv = y[(size_t)row*DI + d];
        float gv = yv * siluf_(zv);
        g[r] = gv;
        ss += gv*gv;
    }
    float tot = blockSum256(ss, red);
    float rinv = rsqrtf(tot*(1.f/512.f) + EPS_);
    #pragma unroll
    for (int r=0;r<2;r++){
        int d = tid + r*256;
        ybf[(size_t)row*DI + d] = f2bu(g[r]*rinv*rw[d]);
    }
}

// ------- K9a: LayerNorm rows -------
__global__ __launch_bounds__(256) void k_ln(const float* __restrict__ h,
                                            const float* __restrict__ lw,
                                            const float* __restrict__ lb,
                                            float* __restrict__ out){
    __shared__ float red[4];
    int row = blockIdx.x;
    int tid = threadIdx.x;
    float v = h[(size_t)row*DM + tid];
    float mu = blockSum256(v, red)*(1.f/256.f);
    float d = v - mu;
    float var = blockSum256(d*d, red)*(1.f/256.f);
    out[(size_t)row*DM + tid] = d*rsqrtf(var + EPS_)*lw[tid] + lb[tid];
}

// ------- K9b: partial mean over L -------
__global__ __launch_bounds__(256) void k_meanl(const float* __restrict__ ln,
                                               float* __restrict__ hmp,
                                               int b0){
    int g = blockIdx.x, bl = blockIdx.y;
    int tid = threadIdx.x;
    float s = 0.f;
    for (int i=0;i<128;i++){
        int l = g*128 + i;
        s += ln[(size_t)(bl*L_ + l)*DM + tid];
    }
    hmp[((size_t)(b0+bl)*16 + g)*DM + tid] = s*(1.f/2048.f);
}

// ------- K10: output heads (fp32 out) -------
__global__ __launch_bounds__(256) void k_heads(const float* __restrict__ hmp,
                                               const float* __restrict__ dw,
                                               const float* __restrict__ db,
                                               const float* __restrict__ rw,
                                               const float* __restrict__ rb,
                                               float* __restrict__ out){
    __shared__ float red[4];
    int b = blockIdx.x;
    int tid = threadIdx.x;
    float hv = 0.f;
    #pragma unroll
    for (int g=0; g<16; g++) hv += hmp[((size_t)b*16 + g)*DM + tid];
    float s0 = hv*dw[tid];
    float s1 = hv*rw[tid*3+0];
    float s2 = hv*rw[tid*3+1];
    float s3 = hv*rw[tid*3+2];
    s0 = blockSum256(s0, red);
    s1 = blockSum256(s1, red);
    s2 = blockSum256(s2, red);
    s3 = blockSum256(s3, red);
    if (tid == 0){
        out[b] = s0 + db[0];
        out[16 + b*3 + 0] = s1 + rb[0];
        out[16 + b*3 + 1] = s2 + rb[1];
        out[16 + b*3 + 2] = s3 + rb[2];
    }
}

extern "C" void kernel_launch(void* const* d_in, const int* in_sizes, int n_in,
                              void* d_out, int out_size, void* d_ws, size_t ws_size,
                              hipStream_t stream){
    static const int expSizes[NIN] = {1507328,11776,256,1187840,10240,2560,32,32,32,2048,524288,256,256,256,1,768,3};
    float* out = (float*)d_out;

    if (n_in != NIN){
        k_sentinel<<<1,64,0,stream>>>(out, 9.0e6f);
        return;
    }
    for (int i=0;i<NIN;i++){
        if (in_sizes[i] != expSizes[i]){
            k_sentinel<<<1,64,0,stream>>>(out, (float)(i+1)*1.0e5f);
            return;
        }
    }
    size_t need16 = ((size_t)SLICEOFF + 2048ull*PERROW)*4ull;
    if (ws_size < need16){
        float mb = (float)(ws_size >> 20);
        k_sentinel<<<1,64,0,stream>>>(out, 2.0e7f + mb*131072.f);
        return;
    }

    float* ws = (float*)d_ws;
    int* flags = (int*)d_ws;
    float* stg = ws + STGOFF;
    unsigned short* ipwT = (unsigned short*)(ws + WIPT);
    unsigned short* opwT = (unsigned short*)(ws + WOPT);
    float* hmp = ws + HMPOFF;

    PtrTab pt;
    for (int i=0;i<NIN;i++) pt.p[i] = d_in[i];

    k_detect<<<NIN, 256, 0, stream>>>(pt, flags);
    k_stage<<<dim3(8, NSMALL), 256, 0, stream>>>(pt, flags, stg);
    k_wip<<<dim3(NP, NL), 256, 0, stream>>>(d_in[3], flags+3, ipwT);
    k_wop<<<dim3(DM, NL), 256, 0, stream>>>(d_in[10], flags+10, opwT);

    const float* inp_w = stg + 0;
    const float* inp_b = stg + 11776;
    const float* cw    = stg + 12032;
    const float* cb    = stg + 22272;
    const float* dtb   = stg + 24832;
    const float* alog  = stg + 24864;
    const float* Dp    = stg + 24896;
    const float* rmsw  = stg + 24928;
    const float* lnw   = stg + 26976;
    const float* lnb   = stg + 27232;
    const float* dw    = stg + 27488;
    const float* db    = stg + 27744;
    const float* rw    = stg + 27748;
    const float* rb    = stg + 28516;

    int nsl = 1;
    while (((size_t)SLICEOFF + ((size_t)MROWS/nsl)*PERROW)*4ull > ws_size) nsl <<= 1;
    const size_t R = (size_t)MROWS / nsl;
    const int SB = B_ / nsl;

    float* base = ws + SLICEOFF;
    float* hbuf = base;                              // R*256 f32
    unsigned short* hbf = (unsigned short*)(hbuf + R*DM);  // R*256 bf16 (R*128 fl)
    float* z    = hbuf + R*DM + R*128;               // R*512 f32
    float* xb   = z + R*DI;                          // R*648 f32 (y alias)
    float* yb   = xb;
    float* xcb  = xb + R*XB;                         // R*640 f32
    float* S    = xcb + R*CD;                        // R*512 f32
    float* dt   = S + R*DI;                          // R*8
    float* cum  = dt + R*NH;                         // R*8
    unsigned short* ybf = (unsigned short*)(cum + R*NH);   // R*512 bf16 (R*256 fl)

    for (int sl=0; sl<nsl; sl++){
        k_inproj<<<(int)R, 256, 0, stream>>>(d_in[0], flags, (size_t)sl*R*46, inp_w, inp_b, hbuf, hbf);
        for (int li=0; li<NL; li++){
            k_mgemm<0><<<dim3(NP/128, R/128), 256, 0, stream>>>(
                hbf, ipwT + (size_t)li*NP*DM, z, xb, ybf, DM);
            k_conv<<<(int)((R*CD)/256), 256, 0, stream>>>(xb, cw + li*CD*4, cb + li*CD, xcb);
            k_dtcum<<<dim3(NCH,NH,SB), 64, 0, stream>>>(xb, dtb + li*NH, alog + li*NH, dt, cum);
            k_passA<<<dim3(NCH,NH,SB), 256, 0, stream>>>(xcb, dt, cum, Dp + li*NH, yb, S);
            k_combine<<<dim3(NH,SB), 256, 0, stream>>>(cum, S);
            k_finalize<<<dim3(NCH,NH,SB), 256, 0, stream>>>(xcb, cum, S, yb);
            k_gaterms<<<(int)R, 256, 0, stream>>>(z, rmsw + li*DI, yb, ybf);
            k_mgemm<1><<<dim3(DM/128, R/128), 256, 0, stream>>>(
                ybf, opwT + (size_t)li*DM*DI, hbuf, z, hbf, DI);
        }
        k_ln<<<(int)R, 256, 0, stream>>>(hbuf, lnw, lnb, z);
        k_meanl<<<dim3(16,SB), 256, 0, stream>>>(z, hmp, sl*SB);
    }
    k_heads<<<B_, 256, 0, stream>>>(hmp, dw, db, rw, rb, out);
}

// Round 13
// 1881.127 us; speedup vs baseline: 1.8619x; 1.1948x over previous
//
#include <hip/hip_runtime.h>
#include <hip/hip_bf16.h>
#include <math.h>

typedef __hip_bfloat16 bf16;

#define B_ 16
#define L_ 2048
#define DM 256
#define DI 512
#define NH 8
#define HD 64
#define DS 64
#define CD 640
#define DIP 1160
#define XB 648
#define NP 1280
#define NL 4
#define Q_ 64
#define NCH 32
#define MROWS (B_*L_)
#define EPS_ 1e-5f
#define NIN 17
#define NSMALL 14
#define STGOFF 32
#define WIPT 28552
#define WOPT 683912
#define HMPOFF 946056
#define SLICEOFF 1011592
#define PERROW 2648

__device__ __forceinline__ float u2f(unsigned short u){ return __uint_as_float(((unsigned)u)<<16); }
__device__ __forceinline__ unsigned short f2bu(float f){ bf16 h = __float2bfloat16(f); return *(unsigned short*)&h; }
__device__ __forceinline__ float sigmoidf_(float x){ return 1.f/(1.f+expf(-x)); }
__device__ __forceinline__ float siluf_(float x){ return x*sigmoidf_(x); }
__device__ __forceinline__ float softplusf_(float x){ return (x>20.f)? x : log1pf(expf(x)); }

typedef __attribute__((ext_vector_type(8))) short short8v;
typedef __attribute__((ext_vector_type(4))) float float4v;

__device__ const int kN17[NIN] = {1507328,11776,256,1187840,10240,2560,32,32,32,2048,524288,256,256,256,1,768,3};
__device__ const int sIdx[NSMALL] = {1,2,4,5,6,7,8,9,11,12,13,14,15,16};
__device__ const int sNum[NSMALL] = {11776,256,10240,2560,32,32,32,2048,256,256,256,1,768,3};
__device__ const int sOff[NSMALL] = {0,11776,12032,22272,24832,24864,24896,24928,26976,27232,27488,27744,27748,28516};

struct PtrTab { const void* p[NIN]; };

// ---- sentinel writer ----
__global__ __launch_bounds__(64) void k_sentinel(float* out, float v){
    int t = threadIdx.x;
    out[t] = (t==0) ? v : 0.f;
}

// ---- dtype detector ----
__global__ __launch_bounds__(256) void k_detect(PtrTab t, int* flags){
    int i = blockIdx.x;
    int n = kN17[i];
    int S = n < 4096 ? n : 4096;
    const unsigned short* u = (const unsigned short*)t.p[i];
    __shared__ int big, ze, zo, so;
    if (threadIdx.x == 0){ big=0; ze=0; zo=0; so=0; }
    __syncthreads();
    int lbig=0, lze=0, lzo=0, lso=0;
    for (int j=threadIdx.x; j<S; j+=256){
        unsigned short v = u[j];
        int e = (v>>7)&0xFF;
        if (e >= 131) lbig = 1;
        int isz = ((v & 0x7FFF) == 0) ? 1 : 0;
        if (j & 1){ lso++; lzo += isz; } else { lze += isz; }
    }
    if (lbig) atomicOr(&big, 1);
    atomicAdd(&ze, lze); atomicAdd(&zo, lzo); atomicAdd(&so, lso);
    __syncthreads();
    if (threadIdx.x == 0){
        int Se = S - so;
        flags[i] = (big || (so > 0 && 4*ze >= 3*Se && 4*zo <= so)) ? 1 : 0;
    }
}

// ---- stage small arrays ----
__global__ __launch_bounds__(256) void k_stage(PtrTab t, const int* __restrict__ flags,
                                               float* __restrict__ stg){
    int a = blockIdx.y;
    int idx = sIdx[a];
    int n = sNum[a];
    float* dst = stg + sOff[a];
    const void* p = t.p[idx];
    if (flags[idx]){
        const float* s = (const float*)p;
        for (int j=blockIdx.x*256+threadIdx.x; j<n; j += gridDim.x*256) dst[j] = s[j];
    } else {
        const unsigned short* s = (const unsigned short*)p;
        for (int j=blockIdx.x*256+threadIdx.x; j<n; j += gridDim.x*256) dst[j] = u2f(s[j]);
    }
}

// ---- stage in_proj_w transposed+padded ----
__global__ __launch_bounds__(256) void k_wip(const void* __restrict__ src,
                                             const int* __restrict__ flag,
                                             unsigned short* __restrict__ dst){
    int n = blockIdx.x, l = blockIdx.y, k = threadIdx.x;
    unsigned short b = 0;
    if (n < DIP){
        size_t si = ((size_t)l*DM + k)*DIP + n;
        if (flag[0]) b = f2bu(((const float*)src)[si]);
        else         b = ((const unsigned short*)src)[si];
    }
    dst[((size_t)l*NP + n)*DM + k] = b;
}

// ---- stage out_proj_w transposed ----
__global__ __launch_bounds__(256) void k_wop(const void* __restrict__ src,
                                             const int* __restrict__ flag,
                                             unsigned short* __restrict__ dst){
    int n = blockIdx.x, l = blockIdx.y;
    for (int k = threadIdx.x; k < DI; k += 256){
        size_t si = ((size_t)l*DI + k)*DM + n;
        unsigned short b;
        if (flag[0]) b = f2bu(((const float*)src)[si]);
        else         b = ((const unsigned short*)src)[si];
        dst[((size_t)l*DM + n)*DI + k] = b;
    }
}

__device__ __forceinline__ float blockSum256(float v, float* red){
    #pragma unroll
    for (int off=32; off>0; off>>=1) v += __shfl_down(v, off);
    if ((threadIdx.x & 63) == 0) red[threadIdx.x >> 6] = v;
    __syncthreads();
    float s = red[0] + red[1] + red[2] + red[3];
    __syncthreads();
    return s;
}

// ---------------- K1: h = x @ inp_w + inp_b ----------------
__global__ __launch_bounds__(256) void k_inproj(const void* __restrict__ x,
                                                const int* __restrict__ flags,
                                                size_t xoff,
                                                const float* __restrict__ w,
                                                const float* __restrict__ bias,
                                                float* __restrict__ h,
                                                unsigned short* __restrict__ hbf){
    __shared__ float xs[46];
    int row = blockIdx.x;
    int t = threadIdx.x;
    bool f32 = flags[0] != 0;
    if (t < 46){
        size_t j = xoff + (size_t)row*46 + t;
        xs[t] = f32 ? ((const float*)x)[j] : u2f(((const unsigned short*)x)[j]);
    }
    __syncthreads();
    float acc = bias[t];
    #pragma unroll 2
    for (int k=0;k<46;k++) acc += xs[k]*w[k*DM + t];
    h[(size_t)row*DM + t] = acc;
    hbf[(size_t)row*DM + t] = f2bu(acc);
}

// ------- MFMA GEMM (projections) -------
template<int MODE>
__global__ __launch_bounds__(256) void k_mgemm(const unsigned short* __restrict__ A,
                                               const unsigned short* __restrict__ Bt,
                                               float* __restrict__ O1,
                                               float* __restrict__ O2,
                                               unsigned short* __restrict__ O3,
                                               int K){
    __shared__ unsigned short As[128*40];
    __shared__ unsigned short Bs[128*40];
    int tid = threadIdx.x;
    int wave = tid >> 6, lane = tid & 63, quad = lane >> 4, l15 = lane & 15;
    int mbase = blockIdx.y*128, nbase = blockIdx.x*128;
    int wm = (wave & 1)*64, wn = (wave >> 1)*64;
    float4v zero4 = {0.f,0.f,0.f,0.f};
    float4v acc[4][4];
    #pragma unroll
    for (int mi=0;mi<4;mi++)
        #pragma unroll
        for (int ni=0;ni<4;ni++) acc[mi][ni] = zero4;
    for (int k0 = 0; k0 < K; k0 += 32){
        #pragma unroll
        for (int i=0;i<2;i++){
            int c = tid + i*256;
            int row = c >> 2, koff = (c & 3)*8;
            *(uint4*)&As[row*40 + koff] = *(const uint4*)&A[(size_t)(mbase+row)*K + k0 + koff];
            *(uint4*)&Bs[row*40 + koff] = *(const uint4*)&Bt[(size_t)(nbase+row)*K + k0 + koff];
        }
        __syncthreads();
        short8v af[4], bfr[4];
        #pragma unroll
        for (int mi=0;mi<4;mi++) af[mi] = *(const short8v*)&As[(wm + mi*16 + l15)*40 + quad*8];
        #pragma unroll
        for (int ni=0;ni<4;ni++) bfr[ni] = *(const short8v*)&Bs[(wn + ni*16 + l15)*40 + quad*8];
        #pragma unroll
        for (int mi=0;mi<4;mi++)
            #pragma unroll
            for (int ni=0;ni<4;ni++)
                acc[mi][ni] = __builtin_amdgcn_mfma_f32_16x16x32_bf16(af[mi], bfr[ni], acc[mi][ni], 0, 0, 0);
        __syncthreads();
    }
    #pragma unroll
    for (int mi=0;mi<4;mi++){
        #pragma unroll
        for (int ni=0;ni<4;ni++){
            int col = nbase + wn + ni*16 + l15;
            #pragma unroll
            for (int reg=0;reg<4;reg++){
                int grow = mbase + wm + mi*16 + quad*4 + reg;
                float v = acc[mi][ni][reg];
                if (MODE == 0){
                    if (col < DI) O1[(size_t)grow*DI + col] = v;
                    else if (col < DIP) O2[(size_t)grow*XB + (col - DI)] = v;
                } else {
                    float hnew = O1[(size_t)grow*DM + col] + v;
                    O1[(size_t)grow*DM + col] = hnew;
                    O3[(size_t)grow*DM + col] = f2bu(hnew);
                }
            }
        }
    }
}

// ---------------- K3: conv(4) + bias + SiLU -> bf16 xcb ----------------
__global__ __launch_bounds__(256) void k_conv(const float* __restrict__ xb,
                                              const float* __restrict__ cw,
                                              const float* __restrict__ cb,
                                              unsigned short* __restrict__ xc){
    int idx = blockIdx.x*256 + threadIdx.x;
    int c = idx % CD;
    int bl = idx / CD;
    int l = bl & (L_-1);
    float acc = cb[c];
    #pragma unroll
    for (int j=0;j<4;j++){
        int l2 = l - 3 + j;
        if (l2 >= 0) acc += xb[(size_t)(bl-3+j)*XB + c] * cw[c*4 + j];
    }
    xc[(size_t)bl*CD + c] = f2bu(siluf_(acc));
}

// ------- K3b: dt/cum -------
__global__ __launch_bounds__(64) void k_dtcum(const float* __restrict__ xb,
                                              const float* __restrict__ dtb,
                                              const float* __restrict__ alog,
                                              float* __restrict__ dto,
                                              float* __restrict__ cumo){
    int kk = blockIdx.x, h = blockIdx.y, b = blockIdx.z;
    int t = threadIdx.x;
    int l = kk*Q_ + t;
    float raw = xb[(size_t)(b*L_ + l)*XB + CD + h];
    float dtv = softplusf_(raw + dtb[h]);
    float A = -expf(alog[h]);
    float s = dtv * A;
    #pragma unroll
    for (int off=1; off<64; off<<=1){
        float u = __shfl_up(s, off);
        if (t >= off) s += u;
    }
    int base = (b*NH + h)*L_ + l;
    dto[base] = dtv;
    cumo[base] = s;
}

// ------- K4: passS — S_local[n][p] = sum_s w_s B[s][n] X[s][p] via MFMA -------
__global__ __launch_bounds__(256) void k_passS(const unsigned short* __restrict__ xc,
                                               const float* __restrict__ dt,
                                               const float* __restrict__ cum,
                                               float* __restrict__ S){
    __shared__ unsigned short Bw[64*72];   // [n][s] = w_s * B[s][n]
    __shared__ unsigned short Xt[64*72];   // [p][s] = X[s][p]
    __shared__ float sw[64];
    int kk = blockIdx.x, h = blockIdx.y, b = blockIdx.z;
    int tid = threadIdx.x;
    int bh = b*NH + h;
    int l0 = kk*Q_;
    if (tid < 64){
        int base = bh*L_ + l0;
        float c = cum[base + tid];
        float c63 = cum[base + 63];
        sw[tid] = dt[base + tid]*expf(fminf(c63 - c, 0.f));
    }
    __syncthreads();
    int srow = tid >> 4, c0 = (tid & 15)*4;
    #pragma unroll
    for (int i=0;i<4;i++){
        int s = srow + i*16;
        size_t rowbase = (size_t)(b*L_ + l0 + s)*CD;
        ushort4 bv = *(const ushort4*)&xc[rowbase + DI + c0];
        ushort4 xv = *(const ushort4*)&xc[rowbase + h*HD + c0];
        float w = sw[s];
        Bw[(c0+0)*72 + s] = f2bu(w*u2f(bv.x));
        Bw[(c0+1)*72 + s] = f2bu(w*u2f(bv.y));
        Bw[(c0+2)*72 + s] = f2bu(w*u2f(bv.z));
        Bw[(c0+3)*72 + s] = f2bu(w*u2f(bv.w));
        Xt[(c0+0)*72 + s] = xv.x;
        Xt[(c0+1)*72 + s] = xv.y;
        Xt[(c0+2)*72 + s] = xv.z;
        Xt[(c0+3)*72 + s] = xv.w;
    }
    __syncthreads();
    int wave = tid >> 6, lane = tid & 63, quad = lane >> 4, l15 = lane & 15;
    int wn = (wave & 1)*32, wp = (wave >> 1)*32;
    float4v zero4 = {0.f,0.f,0.f,0.f};
    float4v acc[2][2];
    #pragma unroll
    for (int mi=0;mi<2;mi++)
        #pragma unroll
        for (int ni=0;ni<2;ni++) acc[mi][ni] = zero4;
    #pragma unroll
    for (int k0=0;k0<64;k0+=32){
        short8v af[2], bfr[2];
        #pragma unroll
        for (int mi=0;mi<2;mi++) af[mi] = *(const short8v*)&Bw[(wn + mi*16 + l15)*72 + k0 + quad*8];
        #pragma unroll
        for (int ni=0;ni<2;ni++) bfr[ni] = *(const short8v*)&Xt[(wp + ni*16 + l15)*72 + k0 + quad*8];
        #pragma unroll
        for (int mi=0;mi<2;mi++)
            #pragma unroll
            for (int ni=0;ni<2;ni++)
                acc[mi][ni] = __builtin_amdgcn_mfma_f32_16x16x32_bf16(af[mi], bfr[ni], acc[mi][ni], 0, 0, 0);
    }
    size_t Sbase = ((size_t)bh*NCH + kk)*4096;
    #pragma unroll
    for (int mi=0;mi<2;mi++){
        #pragma unroll
        for (int ni=0;ni<2;ni++){
            int p = wp + ni*16 + l15;
            #pragma unroll
            for (int reg=0;reg<4;reg++){
                int n = wn + mi*16 + quad*4 + reg;
                S[Sbase + n*64 + p] = acc[mi][ni][reg];
            }
        }
    }
}

// ------- K5: sequential chunk-state combine -------
__global__ __launch_bounds__(256) void k_combine(const float* __restrict__ cum,
                                                 float* __restrict__ S){
    int h = blockIdx.x, b = blockIdx.y;
    int bh = b*NH + h;
    int tid = threadIdx.x;
    float4 st[4];
    #pragma unroll
    for (int i=0;i<4;i++) st[i] = make_float4(0.f,0.f,0.f,0.f);
    size_t base0 = ((size_t)bh*NCH)*4096 + (size_t)tid*16;
    for (int k=0;k<NCH;k++){
        size_t base = base0 + (size_t)k*4096;
        float dk = expf(fminf(cum[bh*L_ + k*Q_ + 63], 0.f));
        float4 a[4];
        #pragma unroll
        for (int i=0;i<4;i++) a[i] = *(const float4*)&S[base + i*4];
        #pragma unroll
        for (int i=0;i<4;i++) *(float4*)&S[base + i*4] = st[i];
        #pragma unroll
        for (int i=0;i<4;i++){
            st[i].x = a[i].x + dk*st[i].x;
            st[i].y = a[i].y + dk*st[i].y;
            st[i].z = a[i].z + dk*st[i].z;
            st[i].w = a[i].w + dk*st[i].w;
        }
    }
}

// ------- K6: finalize2 — y = M@X + D*x + exp(cum)*C@S_in (single y write) -------
__global__ __launch_bounds__(256) void k_finalize2(const unsigned short* __restrict__ xc,
                                                   const float* __restrict__ dt,
                                                   const float* __restrict__ cum,
                                                   const float* __restrict__ Dp,
                                                   const float* __restrict__ S,
                                                   float* __restrict__ y){
    __shared__ unsigned short Ct[64*72];   // [t][n]
    __shared__ unsigned short Bs[64*72];   // [s][n]
    __shared__ unsigned short Xt[64*72];   // [p][s]
    __shared__ unsigned short St[64*72];   // [p][n] = S_in[n][p]
    __shared__ unsigned short Ml[64*72];   // [t][s]
    __shared__ float sdt[64], scum[64];
    int kk = blockIdx.x, h = blockIdx.y, b = blockIdx.z;
    int tid = threadIdx.x;
    int bh = b*NH + h;
    int l0 = kk*Q_;
    if (tid < 64){
        int base = bh*L_ + l0;
        sdt[tid] = dt[base + tid];
        scum[tid] = cum[base + tid];
    }
    int rr = tid >> 4, c0 = (tid & 15)*4;
    size_t Sbase = ((size_t)bh*NCH + kk)*4096;
    #pragma unroll
    for (int i=0;i<4;i++){
        int r = rr + i*16;
        size_t rowbase = (size_t)(b*L_ + l0 + r)*CD;
        *(ushort4*)&Ct[r*72 + c0] = *(const ushort4*)&xc[rowbase + DI + DS + c0];
        *(ushort4*)&Bs[r*72 + c0] = *(const ushort4*)&xc[rowbase + DI + c0];
        ushort4 xv = *(const ushort4*)&xc[rowbase + h*HD + c0];
        Xt[(c0+0)*72 + r] = xv.x;
        Xt[(c0+1)*72 + r] = xv.y;
        Xt[(c0+2)*72 + r] = xv.z;
        Xt[(c0+3)*72 + r] = xv.w;
        float4 sv = *(const float4*)&S[Sbase + r*64 + c0];
        St[(c0+0)*72 + r] = f2bu(sv.x);
        St[(c0+1)*72 + r] = f2bu(sv.y);
        St[(c0+2)*72 + r] = f2bu(sv.z);
        St[(c0+3)*72 + r] = f2bu(sv.w);
    }
    __syncthreads();
    int wave = tid >> 6, lane = tid & 63, quad = lane >> 4, l15 = lane & 15;
    int wt = (wave & 1)*32, wc = (wave >> 1)*32;
    float4v zero4 = {0.f,0.f,0.f,0.f};
    // G = C @ B^T  -> M
    {
        float4v acc[2][2];
        #pragma unroll
        for (int mi=0;mi<2;mi++)
            #pragma unroll
            for (int ni=0;ni<2;ni++) acc[mi][ni] = zero4;
        #pragma unroll
        for (int k0=0;k0<64;k0+=32){
            short8v af[2], bfr[2];
            #pragma unroll
            for (int mi=0;mi<2;mi++) af[mi] = *(const short8v*)&Ct[(wt + mi*16 + l15)*72 + k0 + quad*8];
            #pragma unroll
            for (int ni=0;ni<2;ni++) bfr[ni] = *(const short8v*)&Bs[(wc + ni*16 + l15)*72 + k0 + quad*8];
            #pragma unroll
            for (int mi=0;mi<2;mi++)
                #pragma unroll
                for (int ni=0;ni<2;ni++)
                    acc[mi][ni] = __builtin_amdgcn_mfma_f32_16x16x32_bf16(af[mi], bfr[ni], acc[mi][ni], 0, 0, 0);
        }
        #pragma unroll
        for (int mi=0;mi<2;mi++){
            #pragma unroll
            for (int ni=0;ni<2;ni++){
                int s = wc + ni*16 + l15;
                #pragma unroll
                for (int reg=0;reg<4;reg++){
                    int t = wt + mi*16 + quad*4 + reg;
                    float m = (s <= t) ? acc[mi][ni][reg]*sdt[s]*expf(fminf(scum[t]-scum[s], 0.f)) : 0.f;
                    Ml[t*72 + s] = f2bu(m);
                }
            }
        }
    }
    __syncthreads();
    // Y = M@X + exp(cum_t)*C@S_in + D*x
    {
        float4v a1[2][2], a2[2][2];
        #pragma unroll
        for (int mi=0;mi<2;mi++)
            #pragma unroll
            for (int ni=0;ni<2;ni++){ a1[mi][ni] = zero4; a2[mi][ni] = zero4; }
        #pragma unroll
        for (int k0=0;k0<64;k0+=32){
            short8v mf[2], cf[2], xf[2], sf[2];
            #pragma unroll
            for (int mi=0;mi<2;mi++){
                mf[mi] = *(const short8v*)&Ml[(wt + mi*16 + l15)*72 + k0 + quad*8];
                cf[mi] = *(const short8v*)&Ct[(wt + mi*16 + l15)*72 + k0 + quad*8];
            }
            #pragma unroll
            for (int ni=0;ni<2;ni++){
                xf[ni] = *(const short8v*)&Xt[(wc + ni*16 + l15)*72 + k0 + quad*8];
                sf[ni] = *(const short8v*)&St[(wc + ni*16 + l15)*72 + k0 + quad*8];
            }
            #pragma unroll
            for (int mi=0;mi<2;mi++)
                #pragma unroll
                for (int ni=0;ni<2;ni++){
                    a1[mi][ni] = __builtin_amdgcn_mfma_f32_16x16x32_bf16(mf[mi], xf[ni], a1[mi][ni], 0, 0, 0);
                    a2[mi][ni] = __builtin_amdgcn_mfma_f32_16x16x32_bf16(cf[mi], sf[ni], a2[mi][ni], 0, 0, 0);
                }
        }
        float Dh = Dp[h];
        #pragma unroll
        for (int mi=0;mi<2;mi++){
            #pragma unroll
            for (int ni=0;ni<2;ni++){
                int p = wc + ni*16 + l15;
                #pragma unroll
                for (int reg=0;reg<4;reg++){
                    int t = wt + mi*16 + quad*4 + reg;
                    float e = expf(fminf(scum[t], 0.f));
                    float xval = u2f(Xt[p*72 + t]);
                    y[(size_t)(b*L_ + l0 + t)*DI + h*HD + p] = a1[mi][ni][reg] + e*a2[mi][ni][reg] + Dh*xval;
                }
            }
        }
    }
}

// ------- K7: gate + RMSNorm -> bf16 y -------
__global__ __launch_bounds__(256) void k_gaterms(const float* __restrict__ z,
                                                 const float* __restrict__ rw,
                                                 const float* __restrict__ y,
                                                 unsigned short* __restrict__ ybf){
    __shared__ float red[4];
    int row = blockIdx.x;
    int tid = threadIdx.x;
    float g[2]; float ss = 0.f;
    #pragma unroll
    for (int r=0;r<2;r++){
        int d = tid + r*256;
        float zv = z[(size_t)row*DI + d];
        float yv = y[(size_t)row*DI + d];
        float gv = yv * siluf_(zv);
        g[r] = gv;
        ss += gv*gv;
    }
    float tot = blockSum256(ss, red);
    float rinv = rsqrtf(tot*(1.f/512.f) + EPS_);
    #pragma unroll
    for (int r=0;r<2;r++){
        int d = tid + r*256;
        ybf[(size_t)row*DI + d] = f2bu(g[r]*rinv*rw[d]);
    }
}

// ------- K9a: LayerNorm rows -------
__global__ __launch_bounds__(256) void k_ln(const float* __restrict__ h,
                                            const float* __restrict__ lw,
                                            const float* __restrict__ lb,
                                            float* __restrict__ out){
    __shared__ float red[4];
    int row = blockIdx.x;
    int tid = threadIdx.x;
    float v = h[(size_t)row*DM + tid];
    float mu = blockSum256(v, red)*(1.f/256.f);
    float d = v - mu;
    float var = blockSum256(d*d, red)*(1.f/256.f);
    out[(size_t)row*DM + tid] = d*rsqrtf(var + EPS_)*lw[tid] + lb[tid];
}

// ------- K9b: partial mean over L -------
__global__ __launch_bounds__(256) void k_meanl(const float* __restrict__ ln,
                                               float* __restrict__ hmp,
                                               int b0){
    int g = blockIdx.x, bl = blockIdx.y;
    int tid = threadIdx.x;
    float s = 0.f;
    for (int i=0;i<128;i++){
        int l = g*128 + i;
        s += ln[(size_t)(bl*L_ + l)*DM + tid];
    }
    hmp[((size_t)(b0+bl)*16 + g)*DM + tid] = s*(1.f/2048.f);
}

// ------- K10: output heads -------
__global__ __launch_bounds__(256) void k_heads(const float* __restrict__ hmp,
                                               const float* __restrict__ dw,
                                               const float* __restrict__ db,
                                               const float* __restrict__ rw,
                                               const float* __restrict__ rb,
                                               float* __restrict__ out){
    __shared__ float red[4];
    int b = blockIdx.x;
    int tid = threadIdx.x;
    float hv = 0.f;
    #pragma unroll
    for (int g=0; g<16; g++) hv += hmp[((size_t)b*16 + g)*DM + tid];
    float s0 = hv*dw[tid];
    float s1 = hv*rw[tid*3+0];
    float s2 = hv*rw[tid*3+1];
    float s3 = hv*rw[tid*3+2];
    s0 = blockSum256(s0, red);
    s1 = blockSum256(s1, red);
    s2 = blockSum256(s2, red);
    s3 = blockSum256(s3, red);
    if (tid == 0){
        out[b] = s0 + db[0];
        out[16 + b*3 + 0] = s1 + rb[0];
        out[16 + b*3 + 1] = s2 + rb[1];
        out[16 + b*3 + 2] = s3 + rb[2];
    }
}

extern "C" void kernel_launch(void* const* d_in, const int* in_sizes, int n_in,
                              void* d_out, int out_size, void* d_ws, size_t ws_size,
                              hipStream_t stream){
    static const int expSizes[NIN] = {1507328,11776,256,1187840,10240,2560,32,32,32,2048,524288,256,256,256,1,768,3};
    float* out = (float*)d_out;

    if (n_in != NIN){
        k_sentinel<<<1,64,0,stream>>>(out, 9.0e6f);
        return;
    }
    for (int i=0;i<NIN;i++){
        if (in_sizes[i] != expSizes[i]){
            k_sentinel<<<1,64,0,stream>>>(out, (float)(i+1)*1.0e5f);
            return;
        }
    }
    size_t need16 = ((size_t)SLICEOFF + 2048ull*PERROW)*4ull;
    if (ws_size < need16){
        float mb = (float)(ws_size >> 20);
        k_sentinel<<<1,64,0,stream>>>(out, 2.0e7f + mb*131072.f);
        return;
    }

    float* ws = (float*)d_ws;
    int* flags = (int*)d_ws;
    float* stg = ws + STGOFF;
    unsigned short* ipwT = (unsigned short*)(ws + WIPT);
    unsigned short* opwT = (unsigned short*)(ws + WOPT);
    float* hmp = ws + HMPOFF;

    PtrTab pt;
    for (int i=0;i<NIN;i++) pt.p[i] = d_in[i];

    k_detect<<<NIN, 256, 0, stream>>>(pt, flags);
    k_stage<<<dim3(8, NSMALL), 256, 0, stream>>>(pt, flags, stg);
    k_wip<<<dim3(NP, NL), 256, 0, stream>>>(d_in[3], flags+3, ipwT);
    k_wop<<<dim3(DM, NL), 256, 0, stream>>>(d_in[10], flags+10, opwT);

    const float* inp_w = stg + 0;
    const float* inp_b = stg + 11776;
    const float* cw    = stg + 12032;
    const float* cb    = stg + 22272;
    const float* dtb   = stg + 24832;
    const float* alog  = stg + 24864;
    const float* Dp    = stg + 24896;
    const float* rmsw  = stg + 24928;
    const float* lnw   = stg + 26976;
    const float* lnb   = stg + 27232;
    const float* dw    = stg + 27488;
    const float* db    = stg + 27744;
    const float* rw    = stg + 27748;
    const float* rb    = stg + 28516;

    int nsl = 1;
    while (((size_t)SLICEOFF + ((size_t)MROWS/nsl)*PERROW)*4ull > ws_size) nsl <<= 1;
    const size_t R = (size_t)MROWS / nsl;
    const int SB = B_ / nsl;

    float* base = ws + SLICEOFF;
    float* hbuf = base;                                    // R*256 f32
    unsigned short* hbf = (unsigned short*)(hbuf + R*DM);  // R*256 bf16
    float* z    = hbuf + R*DM + R*128;                     // R*512 f32
    float* xb   = z + R*DI;                                // R*648 f32 (y alias)
    float* yb   = xb;
    unsigned short* xcb = (unsigned short*)(xb + R*XB);    // R*640 bf16 (R*320 fl)
    float* S    = xb + R*XB + R*320;                       // R*512 f32
    float* dt   = S + R*DI;                                // R*8
    float* cum  = dt + R*NH;                               // R*8
    unsigned short* ybf = (unsigned short*)(cum + R*NH);   // R*512 bf16 (R*256 fl)

    for (int sl=0; sl<nsl; sl++){
        k_inproj<<<(int)R, 256, 0, stream>>>(d_in[0], flags, (size_t)sl*R*46, inp_w, inp_b, hbuf, hbf);
        for (int li=0; li<NL; li++){
            k_mgemm<0><<<dim3(NP/128, R/128), 256, 0, stream>>>(
                hbf, ipwT + (size_t)li*NP*DM, z, xb, ybf, DM);
            k_conv<<<(int)((R*CD)/256), 256, 0, stream>>>(xb, cw + li*CD*4, cb + li*CD, xcb);
            k_dtcum<<<dim3(NCH,NH,SB), 64, 0, stream>>>(xb, dtb + li*NH, alog + li*NH, dt, cum);
            k_passS<<<dim3(NCH,NH,SB), 256, 0, stream>>>(xcb, dt, cum, S);
            k_combine<<<dim3(NH,SB), 256, 0, stream>>>(cum, S);
            k_finalize2<<<dim3(NCH,NH,SB), 256, 0, stream>>>(xcb, dt, cum, Dp + li*NH, S, yb);
            k_gaterms<<<(int)R, 256, 0, stream>>>(z, rmsw + li*DI, yb, ybf);
            k_mgemm<1><<<dim3(DM/128, R/128), 256, 0, stream>>>(
                ybf, opwT + (size_t)li*DM*DI, hbuf, z, hbf, DI);
        }
        k_ln<<<(int)R, 256, 0, stream>>>(hbuf, lnw, lnb, z);
        k_meanl<<<dim3(16,SB), 256, 0, stream>>>(z, hmp, sl*SB);
    }
    k_heads<<<B_, 256, 0, stream>>>(hmp, dw, db, rw, rb, out);
}